// Round 3
// baseline (1237.006 us; speedup 1.0000x reference)
//
#include <hip/hip_runtime.h>
#include <cstddef>

typedef _Float16 half8 __attribute__((ext_vector_type(8)));
typedef _Float16 half4 __attribute__((ext_vector_type(4)));
typedef float f32x4 __attribute__((ext_vector_type(4)));

#define MFMA32(A, B, C) __builtin_amdgcn_mfma_f32_16x16x32_f16(A, B, C, 0, 0, 0)
#define MFMA16(A, B, C) __builtin_amdgcn_mfma_f32_16x16x16f16(A, B, C, 0, 0, 0)

// ============ kprep1: per (b,t): A, chol (in-wave shuffle), Ainv, klc, P(f16), c' ============
__global__ void kprep1_kernel(const float* __restrict__ Kg,
                              const float* __restrict__ kg,
                              const float* __restrict__ ug,
                              const float* __restrict__ Qd,
                              const float* __restrict__ Q0d,
                              float* __restrict__ Ainv,
                              float* __restrict__ klc,
                              _Float16* __restrict__ P16,
                              float* __restrict__ cg) {
  int tid = threadIdx.x;
  int wv = tid >> 6, ln = tid & 63;
  size_t bt = (size_t)blockIdx.x * 4 + wv;
  int t = (int)(bt & 255);
  __shared__ float Ks[4][128][20];
  __shared__ float qs[4][128];
  __shared__ float vvs[4][128];
  __shared__ float Asm[4][16][20];
  __shared__ float LiL[4][16][20];
  __shared__ float AiS[4][16][20];
  __shared__ float yps[4][4][16];
  __shared__ float yvs[4][16];

  const float* kp = Kg + bt * 2048;
  for (int i = ln; i < 2048; i += 64) Ks[wv][i >> 4][i & 15] = kp[i];
  for (int l = ln; l < 128; l += 64) {
    float q = (t == 0) ? Q0d[l] : Qd[l];
    qs[wv][l] = q;
    float v = Qd[l] * kg[bt * 128 + l];
    if (t > 0 && l < 64) v += ug[bt * 64 + l];
    vvs[wv][l] = v;
  }
  __syncthreads();
  // A = I + K^T diag(q) K : 4 entries per lane
  {
    int r = ln & 15, c0 = (ln >> 4) << 2;
    float a0 = 0, a1 = 0, a2 = 0, a3 = 0;
    for (int l = 0; l < 128; ++l) {
      float kq = Ks[wv][l][r] * qs[wv][l];
      const float* row = &Ks[wv][l][c0];
      a0 += kq * row[0]; a1 += kq * row[1]; a2 += kq * row[2]; a3 += kq * row[3];
    }
    Asm[wv][r][c0 + 0] = a0 + ((r == c0 + 0) ? 1.f : 0.f);
    Asm[wv][r][c0 + 1] = a1 + ((r == c0 + 1) ? 1.f : 0.f);
    Asm[wv][r][c0 + 2] = a2 + ((r == c0 + 2) ? 1.f : 0.f);
    Asm[wv][r][c0 + 3] = a3 + ((r == c0 + 3) ? 1.f : 0.f);
  }
  // y2 = K^T (Q*k + upad) partials
  {
    int r = ln & 15, seg = ln >> 4;
    float s = 0.f;
    for (int l = seg * 32; l < seg * 32 + 32; ++l) s += Ks[wv][l][r] * vvs[wv][l];
    yps[wv][seg][r] = s;
  }
  __syncthreads();
  // in-wave Cholesky + L^-1 on lanes 0-15 (row i / column cc per lane)
  if (ln < 16) {
    int i = ln;
    float ar[16], Lr[16];
#pragma unroll
    for (int j = 0; j < 16; ++j) ar[j] = Asm[wv][i][j];
    float ld = 0.f;
#pragma unroll
    for (int j = 0; j < 16; ++j) {
      float ajj = __shfl(ar[j], j, 64);
      float d = sqrtf(ajj);
      ld += __logf(d);
      float li = ar[j] / d;
      li = (i >= j) ? li : 0.f;
      Lr[j] = li;
#pragma unroll
      for (int k2 = j; k2 < 16; ++k2) {
        float lk = __shfl(li, k2, 64);
        ar[k2] -= li * lk;
      }
    }
    int cc = i;
    float Lic[16];
#pragma unroll
    for (int ii = 0; ii < 16; ++ii) {
      float s = (ii == cc) ? 1.f : 0.f;
#pragma unroll
      for (int p = 0; p < 16; ++p) {
        if (p < ii) {
          float Lip = __shfl(Lr[p], ii, 64);
          s -= Lip * Lic[p];
        }
      }
      float dii = __shfl(Lr[ii], ii, 64);
      float v = s / dii;
      Lic[ii] = (ii >= cc) ? v : 0.f;
    }
    float tr = 0.f;
#pragma unroll
    for (int ii = 0; ii < 16; ++ii) { tr += Lic[ii] * Lic[ii]; LiL[wv][cc][ii] = Lic[ii]; }
    tr += __shfl_xor(tr, 1); tr += __shfl_xor(tr, 2);
    tr += __shfl_xor(tr, 4); tr += __shfl_xor(tr, 8);
    if (cc == 0) klc[bt] = 0.5f * (tr - 16.f + 2.f * ld);
    yvs[wv][cc] = yps[wv][0][cc] + yps[wv][1][cc] + yps[wv][2][cc] + yps[wv][3][cc];
  }
  __syncthreads();
  // Ainv = L^-T L^-1
  {
    int r = ln & 15, c0 = (ln >> 4) << 2;
    float a0 = 0, a1 = 0, a2 = 0, a3 = 0;
    for (int ii = 0; ii < 16; ++ii) {
      float lir = LiL[wv][r][ii];
      a0 += lir * LiL[wv][c0 + 0][ii];
      a1 += lir * LiL[wv][c0 + 1][ii];
      a2 += lir * LiL[wv][c0 + 2][ii];
      a3 += lir * LiL[wv][c0 + 3][ii];
    }
    AiS[wv][r][c0 + 0] = a0; AiS[wv][r][c0 + 1] = a1;
    AiS[wv][r][c0 + 2] = a2; AiS[wv][r][c0 + 3] = a3;
    f32x4 av = {a0, a1, a2, a3};
    *(f32x4*)&Ainv[bt * 256 + r * 16 + c0] = av;
  }
  __syncthreads();
  // P = q*(K Ainv) -> f16 ; c' = q*k - P.y2
  {
#pragma unroll
    for (int li = 0; li < 2; ++li) {
      int l = ln * 2 + li;
      f32x4 acc0 = {0,0,0,0}, acc1v = {0,0,0,0}, acc2v = {0,0,0,0}, acc3v = {0,0,0,0};
      for (int j = 0; j < 16; ++j) {
        float kj = Ks[wv][l][j];
        acc0 += kj * *(const f32x4*)&AiS[wv][j][0];
        acc1v += kj * *(const f32x4*)&AiS[wv][j][4];
        acc2v += kj * *(const f32x4*)&AiS[wv][j][8];
        acc3v += kj * *(const f32x4*)&AiS[wv][j][12];
      }
      float ql = qs[wv][l];
      float cp = ql * kg[bt * 128 + l];
      float pv[16];
#pragma unroll
      for (int e = 0; e < 4; ++e) {
        pv[e] = ql * acc0[e]; pv[4 + e] = ql * acc1v[e];
        pv[8 + e] = ql * acc2v[e]; pv[12 + e] = ql * acc3v[e];
      }
      half8 ph0, ph1;
#pragma unroll
      for (int r = 0; r < 16; ++r) {
        cp -= pv[r] * yvs[wv][r];
        if (r < 8) ph0[r] = (_Float16)pv[r]; else ph1[r - 8] = (_Float16)pv[r];
      }
      *(half8*)&P16[bt * 2048 + l * 16] = ph0;
      *(half8*)&P16[bt * 2048 + l * 16 + 8] = ph1;
      cg[bt * 128 + l] = cp;
    }
  }
}

// ============ kprepR: R_t = K_t^T W2^T (16x256 f16) via MFMA, W2 in LDS ============
__global__ void kprepR_kernel(const float* __restrict__ Kg,
                              const float* __restrict__ W2,
                              _Float16* __restrict__ Rg) {
  int tid = threadIdx.x;
  int wv = tid >> 6, ln = tid & 63;
  int g = ln >> 4, c = ln & 15;
  __shared__ _Float16 W2h[256 * 136];
  for (int i = tid; i < 32768; i += 256) W2h[(i >> 7) * 136 + (i & 127)] = (_Float16)W2[i];
  __syncthreads();
  for (int it = 0; it < 16; ++it) {
    size_t bt = (size_t)blockIdx.x * 16 + it;
    half8 kA[4];
#pragma unroll
    for (int kt = 0; kt < 4; ++kt)
#pragma unroll
      for (int j = 0; j < 8; ++j)
        kA[kt][j] = (_Float16)Kg[bt * 2048 + (size_t)(kt * 32 + g * 8 + j) * 16 + c];
#pragma unroll
    for (int i = 0; i < 4; ++i) {
      int tile = wv * 4 + i;
      f32x4 acc = {0, 0, 0, 0};
#pragma unroll
      for (int kt = 0; kt < 4; ++kt) {
        half8 bf = *(const half8*)&W2h[(tile * 16 + c) * 136 + kt * 32 + g * 8];
        acc = MFMA32(kA[kt], bf, acc);
      }
#pragma unroll
      for (int r = 0; r < 4; ++r)
        Rg[bt * 4096 + (size_t)(g * 4 + r) * 256 + tile * 16 + c] = (_Float16)acc[r];
    }
  }
}

// ============ kc: per (t,b): z_p output + zpc = z_p - K Ainv (K^T z_p + ew) ============
__global__ void kc_kernel(const float* __restrict__ Kg,
                          const float* __restrict__ epsz,
                          const float* __restrict__ epsw,
                          const float* __restrict__ Qd,
                          const float* __restrict__ Q0d,
                          const float* __restrict__ Ainv,
                          float* __restrict__ out_zf,
                          float* __restrict__ out_zp,
                          int wzp) {
  int idx = blockIdx.x;
  int t = idx >> 6, b = idx & 63;
  int bt = b * 256 + t;
  __shared__ float Ks[128][16];
  __shared__ float Ai[16][16];
  __shared__ float zp[16][129];
  __shared__ float hh[16][17];
  __shared__ float ww[16][17];
  __shared__ float sq[128];
  const float* kp = Kg + (size_t)bt * 2048;
  for (int i = threadIdx.x; i < 2048; i += 256) ((float*)Ks)[i] = kp[i];
  ((float*)Ai)[threadIdx.x] = Ainv[(size_t)bt * 256 + threadIdx.x];
  const float* q = (t == 0) ? Q0d : Qd;
  if (threadIdx.x < 128) sq[threadIdx.x] = sqrtf(q[threadIdx.x]);
  __syncthreads();
  for (int i = threadIdx.x; i < 2048; i += 256) {
    int s = i >> 7, l = i & 127;
    float v = sq[l] * epsz[(((size_t)t * 16 + s) * 64 + b) * 128 + l];
    zp[s][l] = v;
    if (wzp) out_zp[(((size_t)s * 64 + b) * 256 + t) * 128 + l] = v;
  }
  __syncthreads();
  {
    int s = threadIdx.x >> 4, r = threadIdx.x & 15;
    float acc = epsw[(((size_t)t * 16 + s) * 64 + b) * 16 + r];
    for (int l = 0; l < 128; ++l) acc += Ks[l][r] * zp[s][l];
    hh[s][r] = acc;
  }
  __syncthreads();
  {
    int s = threadIdx.x >> 4, r = threadIdx.x & 15;
    float acc = 0.f;
    for (int j = 0; j < 16; ++j) acc += Ai[r][j] * hh[s][j];
    ww[s][r] = acc;
  }
  __syncthreads();
  for (int i = threadIdx.x; i < 2048; i += 256) {
    int s = i >> 7, l = i & 127;
    float acc = 0.f;
    for (int r = 0; r < 16; ++r) acc += Ks[l][r] * ww[s][r];
    out_zf[(((size_t)s * 64 + b) * 256 + t) * 128 + l] = zp[s][l] - acc;
  }
}

// ============ fallback: rebuild out_zp after kscan (when R lives in out_zp) ============
__global__ void kzp_kernel(const float* __restrict__ epsz,
                           const float* __restrict__ Qd,
                           const float* __restrict__ Q0d,
                           float* __restrict__ out_zp) {
  for (size_t i = (size_t)blockIdx.x * blockDim.x + threadIdx.x; i < (size_t)33554432;
       i += (size_t)gridDim.x * blockDim.x) {
    int l = (int)(i & 127);
    int t = (int)((i >> 7) & 255);
    int sb = (int)(i >> 15);
    int s = sb >> 6, b = sb & 63;
    float q = (t == 0) ? Q0d[l] : Qd[l];
    out_zp[i] = sqrtf(q) * epsz[(((size_t)t * 16 + s) * 64 + b) * 128 + l];
  }
}

// ============ kscan: one WG per batch b; 2 barriers/step ============
__launch_bounds__(256, 1)
__global__ void kscan_kernel(const float* __restrict__ ug,
                             const float* __restrict__ Kg,
                             const float* __restrict__ W1,
                             const float* __restrict__ W2,
                             const float* __restrict__ m_init,
                             const float* __restrict__ Qd,
                             const float* __restrict__ Q0d,
                             const _Float16* __restrict__ Pg,
                             const float* __restrict__ cg,
                             const _Float16* __restrict__ Rg,
                             const float* __restrict__ klc,
                             float* __restrict__ out_zf,
                             float* __restrict__ out_mf,
                             float* __restrict__ out_kl) {
  const int b = blockIdx.x;
  const int tid = threadIdx.x;
  const int wv = tid >> 6;
  const int ln = tid & 63;
  const int g = ln >> 4;
  const int c = ln & 15;

  // LDS: rotation-placed 16B granules: granule(s,lg) at byte lg*256 + ((s+lg)&15)*16
  __shared__ __align__(16) _Float16 svh[2048];  // z hi  (16 samples x 128 L)
  __shared__ __align__(16) _Float16 svl[2048];  // z lo
  __shared__ __align__(16) _Float16 hb[4096];   // tanh  (16 samples x 256 H)
  __shared__ float h2p[4][320];                 // per-wave h2 partials [w][c*20+g*4+j]
  __shared__ float qpp[2][64];

  // ---- static weight A-frags ----
  half8 w1f[4][4];
#pragma unroll
  for (int mt = 0; mt < 4; ++mt)
#pragma unroll
    for (int kt = 0; kt < 4; ++kt) {
      half8 v;
#pragma unroll
      for (int j = 0; j < 8; ++j)
        v[j] = (_Float16)W1[(size_t)(kt * 32 + g * 8 + j) * 256 + (wv * 64 + mt * 16 + c)];
      w1f[mt][kt] = v;
    }
  half8 w2f[2][8];
#pragma unroll
  for (int mt = 0; mt < 2; ++mt)
#pragma unroll
    for (int kt = 0; kt < 8; ++kt) {
      half8 v;
#pragma unroll
      for (int j = 0; j < 8; ++j)
        v[j] = (_Float16)W2[(size_t)(kt * 32 + g * 8 + j) * 128 + (wv * 32 + mt * 16 + c)];
      w2f[mt][kt] = v;
    }

  f32x4 qiv[2], qiv0[2];
#pragma unroll
  for (int mt = 0; mt < 2; ++mt) {
    f32x4 q = *(const f32x4*)&Qd[wv * 32 + mt * 16 + g * 4];
    f32x4 q0 = *(const f32x4*)&Q0d[wv * 32 + mt * 16 + g * 4];
#pragma unroll
    for (int r = 0; r < 4; ++r) { qiv[mt][r] = 1.f / q[r]; qiv0[mt][r] = 1.f / q0[r]; }
  }

  f32x4 zreg[2];

  // ---- double-buffered staged registers ----
  float kAf0[2][4], kAf1[2][4];
  half4 rf0[4], rf1[4];
  half4 pf0[2], pf1[2];
  f32x4 cv0[2], cv1[2];
  f32x4 zq0[2], zq1[2];
  f32x4 ur0[2] = {}, ur1[2] = {};
  float kv0 = 0.f, kv1 = 0.f;

#define STAGE(BI, T) do { \
    size_t bt_ = (size_t)b * 256 + (size_t)(T); \
    const float* Kt_ = Kg + bt_ * 2048; \
    _Pragma("unroll") for (int kt = 0; kt < 2; ++kt) \
      _Pragma("unroll") for (int j = 0; j < 4; ++j) \
        kAf##BI[kt][j] = Kt_[(size_t)(wv * 32 + kt * 16 + g * 4 + j) * 16 + c]; \
    _Pragma("unroll") for (int mt = 0; mt < 4; ++mt) \
      rf##BI[mt] = *(const half4*)&Rg[bt_ * 4096 + (size_t)c * 256 + (size_t)(wv * 64 + mt * 16 + g * 4)]; \
    _Pragma("unroll") for (int mt = 0; mt < 2; ++mt) { \
      pf##BI[mt] = *(const half4*)&Pg[bt_ * 2048 + (size_t)(wv * 32 + mt * 16 + c) * 16 + (size_t)(g * 4)]; \
      cv##BI[mt] = *(const f32x4*)&cg[bt_ * 128 + wv * 32 + mt * 16 + g * 4]; \
      zq##BI[mt] = *(const f32x4*)&out_zf[(((size_t)c * 64 + b) * 256 + (size_t)(T)) * 128 + wv * 32 + mt * 16 + g * 4]; \
      if (wv < 2) ur##BI[mt] = *(const f32x4*)&ug[bt_ * 64 + wv * 32 + mt * 16 + g * 4]; \
    } \
    if (tid < 16) kv##BI = klc[bt_]; \
  } while (0)

#define PHASE_A(BI) do { \
    half4 zbh_[2], zbl_[2]; \
    _Pragma("unroll") for (int kt = 0; kt < 2; ++kt) \
      _Pragma("unroll") for (int j = 0; j < 4; ++j) { \
        float x_ = zreg[kt][j]; _Float16 h_ = (_Float16)x_; \
        zbh_[kt][j] = h_; zbl_[kt][j] = (_Float16)(x_ - (float)h_); } \
    f32x4 acc1_[4]; \
    _Pragma("unroll") for (int mt = 0; mt < 4; ++mt) acc1_[mt] = (f32x4){0.f, 0.f, 0.f, 0.f}; \
    _Pragma("unroll") for (int kt = 0; kt < 4; ++kt) { \
      int lg_ = kt * 4 + g; \
      int idx_ = lg_ * 128 + (((c + lg_) & 15) << 3); \
      half8 zh8_ = *(const half8*)&svh[idx_]; \
      half8 zl8_ = *(const half8*)&svl[idx_]; \
      _Pragma("unroll") for (int mt = 0; mt < 4; ++mt) { \
        acc1_[mt] = MFMA32(w1f[mt][kt], zh8_, acc1_[mt]); \
        acc1_[mt] = MFMA32(w1f[mt][kt], zl8_, acc1_[mt]); } } \
    half4 th_[4]; \
    _Pragma("unroll") for (int mt = 0; mt < 4; ++mt) { \
      _Pragma("unroll") for (int r = 0; r < 4; ++r) { \
        float x_ = acc1_[mt][r]; \
        float e_ = __expf(2.f * x_); \
        th_[mt][r] = (_Float16)(1.f - 2.f / (e_ + 1.f)); } \
      int lgw_ = wv * 8 + mt * 2 + (g >> 1); \
      *(half4*)&hb[lgw_ * 128 + (((c + lgw_) & 15) << 3) + ((g & 1) << 2)] = th_[mt]; } \
    f32x4 h2a_ = {0.f, 0.f, 0.f, 0.f}; \
    _Pragma("unroll") for (int kt = 0; kt < 2; ++kt) { \
      half4 ka_; \
      _Pragma("unroll") for (int j = 0; j < 4; ++j) ka_[j] = (_Float16)kAf##BI[kt][j]; \
      h2a_ = MFMA16(ka_, zbh_[kt], h2a_); \
      h2a_ = MFMA16(ka_, zbl_[kt], h2a_); } \
    _Pragma("unroll") for (int mt = 0; mt < 4; ++mt) h2a_ = MFMA16(rf##BI[mt], th_[mt], h2a_); \
    *(f32x4*)&h2p[wv][c * 20 + g * 4] = h2a_; \
  } while (0)

#define EPILOG(BI, T, QIV, MV) do { \
    f32x4 h2v_ = *(const f32x4*)&h2p[0][c * 20 + g * 4]; \
    h2v_ += *(const f32x4*)&h2p[1][c * 20 + g * 4]; \
    h2v_ += *(const f32x4*)&h2p[2][c * 20 + g * 4]; \
    h2v_ += *(const f32x4*)&h2p[3][c * 20 + g * 4]; \
    half4 h2h_, h2l_; \
    _Pragma("unroll") for (int j = 0; j < 4; ++j) { \
      _Float16 h_ = (_Float16)h2v_[j]; \
      h2h_[j] = h_; h2l_[j] = (_Float16)(h2v_[j] - (float)h_); } \
    float qpl_ = 0.f; \
    _Pragma("unroll") for (int mt = 0; mt < 2; ++mt) { \
      f32x4 z4_ = {0.f, 0.f, 0.f, 0.f}; \
      f32x4 macc_ = MFMA16(pf##BI[mt], h2l_, z4_); \
      macc_ = MFMA16(pf##BI[mt], h2h_, macc_); \
      f32x4 dd_ = cv##BI[mt] - macc_; \
      f32x4 mf_ = MV[mt] + dd_; \
      f32x4 zf_ = mf_ + zq##BI[mt]; \
      _Pragma("unroll") for (int r = 0; r < 4; ++r) qpl_ += dd_[r] * dd_[r] * QIV[mt][r]; \
      *(f32x4*)&out_zf[(((size_t)c * 64 + b) * 256 + (size_t)(T)) * 128 + wv * 32 + mt * 16 + g * 4] = zf_; \
      zreg[mt] = zf_; \
      half4 zh4_, zl4_; \
      _Pragma("unroll") for (int r = 0; r < 4; ++r) { \
        _Float16 h_ = (_Float16)zf_[r]; \
        zh4_[r] = h_; zl4_[r] = (_Float16)(zf_[r] - (float)h_); } \
      int lgs_ = wv * 4 + mt * 2 + (g >> 1); \
      int base_ = lgs_ * 128 + (((c + lgs_) & 15) << 3) + ((g & 1) << 2); \
      *(half4*)&svh[base_] = zh4_; \
      *(half4*)&svl[base_] = zl4_; \
      f32x4 ms_ = mf_; \
      _Pragma("unroll") for (int r = 0; r < 4; ++r) { \
        float x_ = ms_[r]; \
        x_ += __shfl_xor(x_, 1); x_ += __shfl_xor(x_, 2); \
        x_ += __shfl_xor(x_, 4); x_ += __shfl_xor(x_, 8); \
        ms_[r] = x_ * 0.0625f; } \
      if (c == 0) \
        *(f32x4*)&out_mf[((size_t)b * 256 + (size_t)(T)) * 128 + wv * 32 + mt * 16 + g * 4] = ms_; \
    } \
    qpl_ += __shfl_xor(qpl_, 16); \
    qpl_ += __shfl_xor(qpl_, 32); \
    if (g == 0) qpp[BI][wv * 16 + c] = qpl_; \
  } while (0)

#define PHASE_B(BI, T, QIV) do { \
    f32x4 acc2_[2]; \
    acc2_[0] = (f32x4){0.f, 0.f, 0.f, 0.f}; \
    acc2_[1] = (f32x4){0.f, 0.f, 0.f, 0.f}; \
    _Pragma("unroll") for (int kt = 0; kt < 8; ++kt) { \
      int lg_ = kt * 4 + g; \
      half8 hf_ = *(const half8*)&hb[lg_ * 128 + (((c + lg_) & 15) << 3)]; \
      _Pragma("unroll") for (int mt = 0; mt < 2; ++mt) \
        acc2_[mt] = MFMA32(w2f[mt][kt], hf_, acc2_[mt]); } \
    f32x4 mv_[2]; \
    _Pragma("unroll") for (int mt = 0; mt < 2; ++mt) { \
      mv_[mt] = zreg[mt] + acc2_[mt]; \
      if (wv < 2) mv_[mt] += ur##BI[mt]; } \
    EPILOG(BI, T, QIV, mv_); \
  } while (0)

#define KL_FIN(PBI, TPREV) do { \
    if (tid < 16) { \
      float v_ = qpp[PBI][tid] + qpp[PBI][16 + tid] + qpp[PBI][32 + tid] + qpp[PBI][48 + tid]; \
      v_ += __shfl_xor(v_, 1); v_ += __shfl_xor(v_, 2); \
      v_ += __shfl_xor(v_, 4); v_ += __shfl_xor(v_, 8); \
      if (tid == 0) out_kl[(size_t)b * 256 + (size_t)(TPREV)] = 0.03125f * v_ + kv##PBI; \
    } \
  } while (0)

  // ---------------- t = 0 ----------------
  STAGE(0, 0);
  STAGE(1, 1);
  {
    f32x4 mv0[2];
#pragma unroll
    for (int mt = 0; mt < 2; ++mt) {
      mv0[mt] = *(const f32x4*)&m_init[wv * 32 + mt * 16 + g * 4];
      if (wv < 2) mv0[mt] += ur0[mt];
    }
    half4 zbh0[2], zbl0[2];
#pragma unroll
    for (int kt = 0; kt < 2; ++kt)
#pragma unroll
      for (int j = 0; j < 4; ++j) {
        float x = mv0[kt][j];
        _Float16 h = (_Float16)x;
        zbh0[kt][j] = h;
        zbl0[kt][j] = (_Float16)(x - (float)h);
      }
    f32x4 h2a = {0.f, 0.f, 0.f, 0.f};
#pragma unroll
    for (int kt = 0; kt < 2; ++kt) {
      half4 ka;
#pragma unroll
      for (int j = 0; j < 4; ++j) ka[j] = (_Float16)kAf0[kt][j];
      h2a = MFMA16(ka, zbh0[kt], h2a);
      h2a = MFMA16(ka, zbl0[kt], h2a);
    }
    *(f32x4*)&h2p[wv][c * 20 + g * 4] = h2a;
    __syncthreads();
    EPILOG(0, 0, qiv0, mv0);
    __syncthreads();
  }

  // ---------------- t = 1..254 (pairs) ----------------
  for (int t = 1; t < 255; t += 2) {
    KL_FIN(0, t - 1);
    STAGE(0, t + 1);
    PHASE_A(1);
    __syncthreads();
    PHASE_B(1, t, qiv);
    __syncthreads();
    KL_FIN(1, t);
    STAGE(1, t + 2);
    PHASE_A(0);
    __syncthreads();
    PHASE_B(0, t + 1, qiv);
    __syncthreads();
  }
  // ---------------- t = 255 ----------------
  KL_FIN(0, 254);
  PHASE_A(1);
  __syncthreads();
  PHASE_B(1, 255, qiv);
  __syncthreads();
  KL_FIN(1, 255);
}

extern "C" void kernel_launch(void* const* d_in, const int* in_sizes, int n_in,
                              void* d_out, int out_size, void* d_ws, size_t ws_size,
                              hipStream_t stream) {
  (void)in_sizes; (void)n_in; (void)out_size;
  const float* u   = (const float*)d_in[0];
  const float* kk  = (const float*)d_in[1];
  const float* Kg  = (const float*)d_in[2];
  const float* epz = (const float*)d_in[3];
  const float* epw = (const float*)d_in[4];
  const float* W1  = (const float*)d_in[5];
  const float* W2  = (const float*)d_in[6];
  const float* mi  = (const float*)d_in[7];
  const float* Qd  = (const float*)d_in[8];
  const float* Q0d = (const float*)d_in[9];

  float* out_zf = (float*)d_out;                      // (S,B,T,L)
  float* out_mf = out_zf + (size_t)33554432;          // (B,T,L)
  float* out_zp = out_mf + (size_t)2097152;           // (S,B,T,L)
  float* out_kl = out_zp + (size_t)33554432;          // (B,T)

  char* ws = (char*)d_ws;
  float* Ainv    = (float*)ws;                        // 16,777,216 B
  float* klc     = (float*)(ws + 16777216);           //     65,536 B
  float* cg      = (float*)(ws + 16842752);           //  8,388,608 B
  _Float16* P16  = (_Float16*)(ws + 25231360);        // 67,108,864 B
  const size_t need_full = 226557952;                 // + R16 134,217,728 B
  bool fb = ws_size < need_full;
  _Float16* R16 = fb ? (_Float16*)out_zp : (_Float16*)(ws + 92340224);
  int wzp = fb ? 0 : 1;

  kprep1_kernel<<<4096, 256, 0, stream>>>(Kg, kk, u, Qd, Q0d, Ainv, klc, P16, cg);
  kprepR_kernel<<<1024, 256, 0, stream>>>(Kg, W2, R16);
  kc_kernel<<<16384, 256, 0, stream>>>(Kg, epz, epw, Qd, Q0d, Ainv, out_zf, out_zp, wzp);
  kscan_kernel<<<64, 256, 0, stream>>>(u, Kg, W1, W2, mi, Qd, Q0d, P16, cg, R16, klc,
                                       out_zf, out_mf, out_kl);
  if (fb) kzp_kernel<<<2048, 256, 0, stream>>>(epz, Qd, Q0d, out_zp);
}

// Round 4
// 1188.076 us; speedup vs baseline: 1.0412x; 1.0412x over previous
//
#include <hip/hip_runtime.h>
#include <cstddef>

typedef _Float16 half8v __attribute__((ext_vector_type(8)));
typedef _Float16 half4v __attribute__((ext_vector_type(4)));
typedef float f32x4 __attribute__((ext_vector_type(4)));

#define MFMA32(A, B, C) __builtin_amdgcn_mfma_f32_16x16x32_f16(A, B, C, 0, 0, 0)
#define MFMA16(A, B, C) __builtin_amdgcn_mfma_f32_16x16x16f16(A, B, C, 0, 0, 0)

// ============ kw2: W2 -> f16 copy (row-major 256x128) ============
__global__ void kw2_kernel(const float* __restrict__ W2, _Float16* __restrict__ w2h) {
  int i = blockIdx.x * 256 + threadIdx.x;
  w2h[i] = (_Float16)W2[i];
}

// ============ kprep1: per (b,t): A, chol (in-wave), Ainv, klc, pf-chunk(f16), c' ============
__global__ void kprep1_kernel(const float* __restrict__ Kg,
                              const float* __restrict__ kg,
                              const float* __restrict__ ug,
                              const float* __restrict__ Qd,
                              const float* __restrict__ Q0d,
                              float* __restrict__ Ainv,
                              float* __restrict__ klc,
                              _Float16* __restrict__ pfb,
                              float* __restrict__ cgp) {
  int tid = threadIdx.x;
  int wv = tid >> 6, ln = tid & 63;
  size_t bt = (size_t)blockIdx.x * 4 + wv;
  int t = (int)(bt & 255);
  __shared__ float Ks[4][128][20];   // later reused as Ps[l][r]
  __shared__ float qs[4][128];
  __shared__ float vvs[4][128];
  __shared__ float Asm[4][16][20];
  __shared__ float LiL[4][16][20];
  __shared__ float AiS[4][16][20];
  __shared__ float yps[4][4][16];
  __shared__ float yvs[4][16];

  const float* kp = Kg + bt * 2048;
  for (int i = ln; i < 2048; i += 64) Ks[wv][i >> 4][i & 15] = kp[i];
  for (int l = ln; l < 128; l += 64) {
    float q = (t == 0) ? Q0d[l] : Qd[l];
    qs[wv][l] = q;
    float v = Qd[l] * kg[bt * 128 + l];
    if (t > 0 && l < 64) v += ug[bt * 64 + l];
    vvs[wv][l] = v;
  }
  __syncthreads();
  {
    int r = ln & 15, c0 = (ln >> 4) << 2;
    float a0 = 0, a1 = 0, a2 = 0, a3 = 0;
    for (int l = 0; l < 128; ++l) {
      float kq = Ks[wv][l][r] * qs[wv][l];
      const float* row = &Ks[wv][l][c0];
      a0 += kq * row[0]; a1 += kq * row[1]; a2 += kq * row[2]; a3 += kq * row[3];
    }
    Asm[wv][r][c0 + 0] = a0 + ((r == c0 + 0) ? 1.f : 0.f);
    Asm[wv][r][c0 + 1] = a1 + ((r == c0 + 1) ? 1.f : 0.f);
    Asm[wv][r][c0 + 2] = a2 + ((r == c0 + 2) ? 1.f : 0.f);
    Asm[wv][r][c0 + 3] = a3 + ((r == c0 + 3) ? 1.f : 0.f);
  }
  {
    int r = ln & 15, seg = ln >> 4;
    float s = 0.f;
    for (int l = seg * 32; l < seg * 32 + 32; ++l) s += Ks[wv][l][r] * vvs[wv][l];
    yps[wv][seg][r] = s;
  }
  __syncthreads();
  if (ln < 16) {
    int i = ln;
    float ar[16], Lr[16];
#pragma unroll
    for (int j = 0; j < 16; ++j) ar[j] = Asm[wv][i][j];
    float ld = 0.f;
#pragma unroll
    for (int j = 0; j < 16; ++j) {
      float ajj = __shfl(ar[j], j, 64);
      float d = sqrtf(ajj);
      ld += __logf(d);
      float li = ar[j] / d;
      li = (i >= j) ? li : 0.f;
      Lr[j] = li;
#pragma unroll
      for (int k2 = j; k2 < 16; ++k2) {
        float lk = __shfl(li, k2, 64);
        ar[k2] -= li * lk;
      }
    }
    int cc = i;
    float Lic[16];
#pragma unroll
    for (int ii = 0; ii < 16; ++ii) {
      float s = (ii == cc) ? 1.f : 0.f;
#pragma unroll
      for (int p = 0; p < 16; ++p) {
        if (p < ii) {
          float Lip = __shfl(Lr[p], ii, 64);
          s -= Lip * Lic[p];
        }
      }
      float dii = __shfl(Lr[ii], ii, 64);
      float v = s / dii;
      Lic[ii] = (ii >= cc) ? v : 0.f;
    }
    float tr = 0.f;
#pragma unroll
    for (int ii = 0; ii < 16; ++ii) { tr += Lic[ii] * Lic[ii]; LiL[wv][cc][ii] = Lic[ii]; }
    tr += __shfl_xor(tr, 1); tr += __shfl_xor(tr, 2);
    tr += __shfl_xor(tr, 4); tr += __shfl_xor(tr, 8);
    if (cc == 0) klc[bt] = 0.5f * (tr - 16.f + 2.f * ld);
    yvs[wv][cc] = yps[wv][0][cc] + yps[wv][1][cc] + yps[wv][2][cc] + yps[wv][3][cc];
  }
  __syncthreads();
  {
    int r = ln & 15, c0 = (ln >> 4) << 2;
    float a0 = 0, a1 = 0, a2 = 0, a3 = 0;
    for (int ii = 0; ii < 16; ++ii) {
      float lir = LiL[wv][r][ii];
      a0 += lir * LiL[wv][c0 + 0][ii];
      a1 += lir * LiL[wv][c0 + 1][ii];
      a2 += lir * LiL[wv][c0 + 2][ii];
      a3 += lir * LiL[wv][c0 + 3][ii];
    }
    AiS[wv][r][c0 + 0] = a0; AiS[wv][r][c0 + 1] = a1;
    AiS[wv][r][c0 + 2] = a2; AiS[wv][r][c0 + 3] = a3;
    f32x4 av = {a0, a1, a2, a3};
    *(f32x4*)&Ainv[bt * 256 + r * 16 + c0] = av;
  }
  __syncthreads();
  // P = q*(K Ainv); c' = q*k - P.y2; store P into Ks (reuse) for fragment gather
  {
#pragma unroll
    for (int li = 0; li < 2; ++li) {
      int l = ln * 2 + li;
      f32x4 acc0 = {0,0,0,0}, acc1v = {0,0,0,0}, acc2v = {0,0,0,0}, acc3v = {0,0,0,0};
      for (int j = 0; j < 16; ++j) {
        float kj = Ks[wv][l][j];
        acc0  += kj * *(const f32x4*)&AiS[wv][j][0];
        acc1v += kj * *(const f32x4*)&AiS[wv][j][4];
        acc2v += kj * *(const f32x4*)&AiS[wv][j][8];
        acc3v += kj * *(const f32x4*)&AiS[wv][j][12];
      }
      float ql = qs[wv][l];
      float cp = ql * kg[bt * 128 + l];
      float pv[16];
#pragma unroll
      for (int e = 0; e < 4; ++e) {
        pv[e] = ql * acc0[e]; pv[4 + e] = ql * acc1v[e];
        pv[8 + e] = ql * acc2v[e]; pv[12 + e] = ql * acc3v[e];
      }
#pragma unroll
      for (int r = 0; r < 16; ++r) cp -= pv[r] * yvs[wv][r];
      cgp[bt * 128 + l] = cp;
#pragma unroll
      for (int r = 0; r < 16; ++r) Ks[wv][l][r] = pv[r];
    }
  }
  __syncthreads();
  // pf chunk: consumer tid ctid=(ci,ln): {P[ci*32+mt*16+c'][g'*4+j], mt=0,1}
  {
    int gp = ln >> 4, cp = ln & 15;
#pragma unroll
    for (int ci = 0; ci < 4; ++ci) {
      half8v o;
#pragma unroll
      for (int mt = 0; mt < 2; ++mt)
#pragma unroll
        for (int j = 0; j < 4; ++j)
          o[mt * 4 + j] = (_Float16)Ks[wv][ci * 32 + mt * 16 + cp][gp * 4 + j];
      *(half8v*)(pfb + bt * 2048 + (size_t)(ci * 64 + ln) * 8) = o;
    }
  }
}

// ============ kprepR: R = (W2 K) fragments + K f16 fragments, coalesced chunk stores ============
__global__ void kprepR_kernel(const float* __restrict__ Kg,
                              const _Float16* __restrict__ w2h,
                              _Float16* __restrict__ rfb,
                              _Float16* __restrict__ kab) {
  int tid = threadIdx.x;
  int wv = tid >> 6, ln = tid & 63;
  int g = ln >> 4, c = ln & 15;
  __shared__ _Float16 Kh[128][20];
  __shared__ _Float16 Rh[16][264];
  for (int it = 0; it < 4; ++it) {
    size_t bt = (size_t)blockIdx.x * 4 + it;
    const float* kp = Kg + bt * 2048;
    for (int i = tid; i < 2048; i += 256) Kh[i >> 4][i & 15] = (_Float16)kp[i];
    __syncthreads();
    half8v kA[4];
#pragma unroll
    for (int kt = 0; kt < 4; ++kt)
#pragma unroll
      for (int j = 0; j < 8; ++j) kA[kt][j] = Kh[kt * 32 + g * 8 + j][c];
#pragma unroll
    for (int i = 0; i < 4; ++i) {
      int tile = wv * 4 + i;
      f32x4 acc = {0, 0, 0, 0};
#pragma unroll
      for (int kt = 0; kt < 4; ++kt) {
        half8v bf = *(const half8v*)&w2h[(size_t)(tile * 16 + c) * 128 + kt * 32 + g * 8];
        acc = MFMA32(kA[kt], bf, acc);
      }
#pragma unroll
      for (int r = 0; r < 4; ++r) Rh[g * 4 + r][tile * 16 + c] = (_Float16)acc[r];
    }
    __syncthreads();
    half8v r0, r1;
#pragma unroll
    for (int mt = 0; mt < 4; ++mt)
#pragma unroll
      for (int j = 0; j < 4; ++j) {
        _Float16 v = Rh[c][wv * 64 + mt * 16 + g * 4 + j];
        if (mt < 2) r0[mt * 4 + j] = v; else r1[(mt - 2) * 4 + j] = v;
      }
    *(half8v*)(rfb + bt * 4096 + (size_t)tid * 16) = r0;
    *(half8v*)(rfb + bt * 4096 + (size_t)tid * 16 + 8) = r1;
    if (kab) {
      half8v ko;
#pragma unroll
      for (int kt = 0; kt < 2; ++kt)
#pragma unroll
        for (int j = 0; j < 4; ++j) ko[kt * 4 + j] = Kh[wv * 32 + kt * 16 + g * 4 + j][c];
      *(half8v*)(kab + bt * 2048 + (size_t)tid * 8) = ko;
    }
    __syncthreads();
  }
}

// ============ kc: per (t,b): z_p out + zpc = z_p - K Ainv (K^T z_p + ew) ============
__global__ void kc_kernel(const float* __restrict__ Kg,
                          const float* __restrict__ epsz,
                          const float* __restrict__ epsw,
                          const float* __restrict__ Qd,
                          const float* __restrict__ Q0d,
                          const float* __restrict__ Ainv,
                          float* __restrict__ out_zf,
                          float* __restrict__ out_zp,
                          float* __restrict__ zpcb,
                          int zw, int wzp) {
  int idx = blockIdx.x;
  int t = idx >> 6, b = idx & 63;
  int bt = b * 256 + t;
  __shared__ float Ks[128][16];
  __shared__ float Ai[16][16];
  __shared__ float zp[16][129];
  __shared__ float hh[16][17];
  __shared__ float ww[16][17];
  __shared__ float sq[128];
  const float* kp = Kg + (size_t)bt * 2048;
  for (int i = threadIdx.x; i < 2048; i += 256) ((float*)Ks)[i] = kp[i];
  ((float*)Ai)[threadIdx.x] = Ainv[(size_t)bt * 256 + threadIdx.x];
  const float* q = (t == 0) ? Q0d : Qd;
  if (threadIdx.x < 128) sq[threadIdx.x] = sqrtf(q[threadIdx.x]);
  __syncthreads();
  for (int i = threadIdx.x; i < 2048; i += 256) {
    int s = i >> 7, l = i & 127;
    float v = sq[l] * epsz[(((size_t)t * 16 + s) * 64 + b) * 128 + l];
    zp[s][l] = v;
    if (wzp) out_zp[(((size_t)s * 64 + b) * 256 + t) * 128 + l] = v;
  }
  __syncthreads();
  {
    int s = threadIdx.x >> 4, r = threadIdx.x & 15;
    float acc = epsw[(((size_t)t * 16 + s) * 64 + b) * 16 + r];
    for (int l = 0; l < 128; ++l) acc += Ks[l][r] * zp[s][l];
    hh[s][r] = acc;
  }
  __syncthreads();
  {
    int s = threadIdx.x >> 4, r = threadIdx.x & 15;
    float acc = 0.f;
    for (int j = 0; j < 16; ++j) acc += Ai[r][j] * hh[s][j];
    ww[s][r] = acc;
  }
  __syncthreads();
  for (int i = threadIdx.x; i < 2048; i += 256) {
    int s = i >> 7, l = i & 127;
    float acc = 0.f;
    for (int r = 0; r < 16; ++r) acc += Ks[l][r] * ww[s][r];
    float v = zp[s][l] - acc;
    if (zw) zpcb[(size_t)bt * 2048 + i] = v;
    else out_zf[(((size_t)s * 64 + b) * 256 + t) * 128 + l] = v;
  }
}

// ============ kzp: rebuild out_zp after kscan (rf lived in out_zp) ============
__global__ void kzp_kernel(const float* __restrict__ epsz,
                           const float* __restrict__ Qd,
                           const float* __restrict__ Q0d,
                           float* __restrict__ out_zp) {
  for (size_t i = (size_t)blockIdx.x * blockDim.x + threadIdx.x; i < (size_t)33554432;
       i += (size_t)gridDim.x * blockDim.x) {
    int l = (int)(i & 127);
    int t = (int)((i >> 7) & 255);
    int sb = (int)(i >> 15);
    int s = sb >> 6, b = sb & 63;
    float q = (t == 0) ? Q0d[l] : Qd[l];
    out_zp[i] = sqrtf(q) * epsz[(((size_t)t * 16 + s) * 64 + b) * 128 + l];
  }
}

// ============ kscan: one WG per batch b; packed-chunk STAGE, split MFMA chains ============
template <bool PK, bool ZW>
__launch_bounds__(256, 1)
__global__ void kscan_kernel(const float* __restrict__ ug,
                             const float* __restrict__ Kg,
                             const float* __restrict__ W1,
                             const float* __restrict__ W2,
                             const float* __restrict__ m_init,
                             const float* __restrict__ Qd,
                             const float* __restrict__ Q0d,
                             const _Float16* __restrict__ pfb,
                             const float* __restrict__ cgp,
                             const _Float16* __restrict__ rfb,
                             const _Float16* __restrict__ kab,
                             const float* __restrict__ zpcb,
                             const float* __restrict__ klcp,
                             float* __restrict__ out_zf,
                             float* __restrict__ out_mf,
                             float* __restrict__ out_kl) {
  const int b = blockIdx.x;
  const int tid = threadIdx.x;
  const int wv = tid >> 6;
  const int ln = tid & 63;
  const int g = ln >> 4;
  const int c = ln & 15;

  __shared__ __align__(16) _Float16 svh[2048];  // z hi: [dim-oct 16][sample-granule rot]
  __shared__ __align__(16) _Float16 svl[2048];
  __shared__ __align__(16) _Float16 hb[4096];   // tanh: [hid-oct 32][sample-granule rot]
  __shared__ float h2p[4][320];
  __shared__ float qpp[2][64];

  half8v w1f[4][4];
#pragma unroll
  for (int mt = 0; mt < 4; ++mt)
#pragma unroll
    for (int kt = 0; kt < 4; ++kt) {
      half8v v;
#pragma unroll
      for (int j = 0; j < 8; ++j)
        v[j] = (_Float16)W1[(size_t)(kt * 32 + g * 8 + j) * 256 + (wv * 64 + mt * 16 + c)];
      w1f[mt][kt] = v;
    }
  half8v w2f[2][8];
#pragma unroll
  for (int mt = 0; mt < 2; ++mt)
#pragma unroll
    for (int kt = 0; kt < 8; ++kt) {
      half8v v;
#pragma unroll
      for (int j = 0; j < 8; ++j)
        v[j] = (_Float16)W2[(size_t)(kt * 32 + g * 8 + j) * 128 + (wv * 32 + mt * 16 + c)];
      w2f[mt][kt] = v;
    }

  f32x4 qiv[2], qiv0[2];
#pragma unroll
  for (int mt = 0; mt < 2; ++mt) {
    f32x4 q = *(const f32x4*)&Qd[wv * 32 + mt * 16 + g * 4];
    f32x4 q0 = *(const f32x4*)&Q0d[wv * 32 + mt * 16 + g * 4];
#pragma unroll
    for (int r = 0; r < 4; ++r) { qiv[mt][r] = 1.f / q[r]; qiv0[mt][r] = 1.f / q0[r]; }
  }

  f32x4 zreg[2];

  // staged double-buffer registers
  half8v pfx0, pfx1, kax0 = {}, kax1 = {}, rfa0, rfa1, rfc0, rfc1;
  float kf0[8], kf1[8];
  f32x4 zq0[2], zq1[2], cv0[2], cv1[2];
  f32x4 ur0[2] = {}, ur1[2] = {};
  float kv0 = 0.f, kv1 = 0.f;

  // pointers advanced by constant strides
  const char* pf_p = (const char*)pfb + (size_t)b * 256 * 4096 + (size_t)tid * 16;
  const char* ka_p = PK ? (const char*)kab + (size_t)b * 256 * 4096 + (size_t)tid * 16
                        : (const char*)pfb;
  const char* K_p = (const char*)Kg + (size_t)b * 256 * 8192 + (size_t)((wv * 32 + g * 4) * 16 + c) * 4;
  const char* rf_p = (const char*)rfb + (size_t)b * 256 * 8192 + (size_t)tid * 32;
  const char* zq_p = ZW ? (const char*)zpcb + (size_t)b * 256 * 8192 + (size_t)(c * 128 + wv * 32 + g * 4) * 4
                        : (const char*)out_zf + ((((size_t)c * 64 + b) * 256) * 128 + wv * 32 + g * 4) * 4;
  const size_t zq_str = ZW ? 8192 : 512;
  const char* cv_p = (const char*)cgp + (size_t)b * 256 * 512 + (size_t)(wv * 32 + g * 4) * 4;
  const char* ur_p = (const char*)ug + (size_t)b * 256 * 256 + (size_t)(wv * 32 + g * 4) * 4;
  const char* kl_p = (const char*)klcp + (size_t)b * 256 * 4;
  char* zf_p = (char*)out_zf + ((((size_t)c * 64 + b) * 256) * 128 + wv * 32 + g * 4) * 4;
  char* mf_p = (char*)out_mf + ((size_t)b * 256 * 128 + wv * 32 + g * 4) * 4;

#define STAGE(BI) do { \
    pfx##BI = *(const half8v*)pf_p; pf_p += 4096; \
    if constexpr (PK) { kax##BI = *(const half8v*)ka_p; ka_p += 4096; } \
    else { _Pragma("unroll") for (int kt_ = 0; kt_ < 2; ++kt_) \
             _Pragma("unroll") for (int j_ = 0; j_ < 4; ++j_) \
               kf##BI[kt_ * 4 + j_] = *(const float*)(K_p + kt_ * 1024 + j_ * 64); \
           K_p += 8192; } \
    rfa##BI = *(const half8v*)rf_p; rfc##BI = *(const half8v*)(rf_p + 16); rf_p += 8192; \
    zq##BI[0] = *(const f32x4*)zq_p; zq##BI[1] = *(const f32x4*)(zq_p + 64); zq_p += zq_str; \
    cv##BI[0] = *(const f32x4*)cv_p; cv##BI[1] = *(const f32x4*)(cv_p + 64); cv_p += 512; \
    if (wv < 2) { ur##BI[0] = *(const f32x4*)ur_p; ur##BI[1] = *(const f32x4*)(ur_p + 64); } \
    ur_p += 256; \
    kv##BI = *(const float*)kl_p; kl_p += 4; \
  } while (0)

#define KAH(BI, KT, DST) do { \
    if constexpr (PK) { _Pragma("unroll") for (int j_ = 0; j_ < 4; ++j_) DST[j_] = kax##BI[(KT) * 4 + j_]; } \
    else { _Pragma("unroll") for (int j_ = 0; j_ < 4; ++j_) DST[j_] = (_Float16)kf##BI[(KT) * 4 + j_]; } \
  } while (0)

#define PHASE_A(BI) do { \
    half4v zbh_[2], zbl_[2]; \
    _Pragma("unroll") for (int kt = 0; kt < 2; ++kt) \
      _Pragma("unroll") for (int j = 0; j < 4; ++j) { \
        float x_ = zreg[kt][j]; _Float16 h_ = (_Float16)x_; \
        zbh_[kt][j] = h_; zbl_[kt][j] = (_Float16)(x_ - (float)h_); } \
    half8v zh8_[4], zl8_[4]; \
    _Pragma("unroll") for (int kt = 0; kt < 4; ++kt) { \
      int row_ = kt * 4 + g; \
      int idx_ = row_ * 128 + (((c + row_) & 15) << 3); \
      zh8_[kt] = *(const half8v*)&svh[idx_]; \
      zl8_[kt] = *(const half8v*)&svl[idx_]; } \
    f32x4 a1h_[4], a1l_[4]; \
    _Pragma("unroll") for (int mt = 0; mt < 4; ++mt) { a1h_[mt] = (f32x4){0,0,0,0}; a1l_[mt] = (f32x4){0,0,0,0}; } \
    _Pragma("unroll") for (int kt = 0; kt < 4; ++kt) \
      _Pragma("unroll") for (int mt = 0; mt < 4; ++mt) { \
        a1h_[mt] = MFMA32(w1f[mt][kt], zh8_[kt], a1h_[mt]); \
        a1l_[mt] = MFMA32(w1f[mt][kt], zl8_[kt], a1l_[mt]); } \
    half4v th_[4]; \
    _Pragma("unroll") for (int mt = 0; mt < 4; ++mt) { \
      _Pragma("unroll") for (int r = 0; r < 4; ++r) { \
        float x_ = a1h_[mt][r] + a1l_[mt][r]; \
        float e_ = __expf(2.f * x_); \
        th_[mt][r] = (_Float16)(1.f - 2.f / (e_ + 1.f)); } \
      int row_ = wv * 8 + mt * 2 + (g >> 1); \
      *(half4v*)&hb[row_ * 128 + (((c + row_) & 15) << 3) + ((g & 1) << 2)] = th_[mt]; } \
    half4v ka0_, ka1_; KAH(BI, 0, ka0_); KAH(BI, 1, ka1_); \
    f32x4 hz_ = {0, 0, 0, 0}; \
    hz_ = MFMA16(ka0_, zbh_[0], hz_); hz_ = MFMA16(ka1_, zbh_[1], hz_); \
    hz_ = MFMA16(ka0_, zbl_[0], hz_); hz_ = MFMA16(ka1_, zbl_[1], hz_); \
    f32x4 hr_ = {0, 0, 0, 0}; \
    _Pragma("unroll") for (int mt = 0; mt < 4; ++mt) { \
      half4v rr_; \
      _Pragma("unroll") for (int j = 0; j < 4; ++j) \
        rr_[j] = (mt < 2) ? rfa##BI[mt * 4 + j] : rfc##BI[(mt - 2) * 4 + j]; \
      hr_ = MFMA16(rr_, th_[mt], hr_); } \
    *(f32x4*)&h2p[wv][c * 20 + g * 4] = hz_ + hr_; \
  } while (0)

#define EPILOG(BI, QIV, MV) do { \
    f32x4 h2v_ = *(const f32x4*)&h2p[0][c * 20 + g * 4]; \
    h2v_ += *(const f32x4*)&h2p[1][c * 20 + g * 4]; \
    h2v_ += *(const f32x4*)&h2p[2][c * 20 + g * 4]; \
    h2v_ += *(const f32x4*)&h2p[3][c * 20 + g * 4]; \
    half4v h2h_, h2l_; \
    _Pragma("unroll") for (int j = 0; j < 4; ++j) { \
      _Float16 h_ = (_Float16)h2v_[j]; \
      h2h_[j] = h_; h2l_[j] = (_Float16)(h2v_[j] - (float)h_); } \
    float qpl_ = 0.f; \
    _Pragma("unroll") for (int mt = 0; mt < 2; ++mt) { \
      half4v pfm_; \
      _Pragma("unroll") for (int j = 0; j < 4; ++j) pfm_[j] = pfx##BI[mt * 4 + j]; \
      f32x4 zz_ = {0, 0, 0, 0}; \
      f32x4 mh_ = MFMA16(pfm_, h2h_, zz_); \
      f32x4 mlv_ = MFMA16(pfm_, h2l_, zz_); \
      f32x4 dd_ = cv##BI[mt] - (mh_ + mlv_); \
      f32x4 mf_ = MV[mt] + dd_; \
      f32x4 zf_ = mf_ + zq##BI[mt]; \
      _Pragma("unroll") for (int r = 0; r < 4; ++r) qpl_ += dd_[r] * dd_[r] * QIV[mt][r]; \
      *(f32x4*)(zf_p + mt * 64) = zf_; \
      zreg[mt] = zf_; \
      half4v zh4_, zl4_; \
      _Pragma("unroll") for (int r = 0; r < 4; ++r) { \
        _Float16 h_ = (_Float16)zf_[r]; \
        zh4_[r] = h_; zl4_[r] = (_Float16)(zf_[r] - (float)h_); } \
      int row_ = wv * 4 + mt * 2 + (g >> 1); \
      int base_ = row_ * 128 + (((c + row_) & 15) << 3) + ((g & 1) << 2); \
      *(half4v*)&svh[base_] = zh4_; \
      *(half4v*)&svl[base_] = zl4_; \
      f32x4 ms_ = mf_; \
      _Pragma("unroll") for (int r = 0; r < 4; ++r) { \
        float x_ = ms_[r]; \
        x_ += __shfl_xor(x_, 1); x_ += __shfl_xor(x_, 2); \
        x_ += __shfl_xor(x_, 4); x_ += __shfl_xor(x_, 8); \
        ms_[r] = x_ * 0.0625f; } \
      if (c == 0) *(f32x4*)(mf_p + mt * 64) = ms_; \
    } \
    zf_p += 512; mf_p += 512; \
    qpl_ += __shfl_xor(qpl_, 16); \
    qpl_ += __shfl_xor(qpl_, 32); \
    if (g == 0) qpp[BI][wv * 16 + c] = qpl_; \
  } while (0)

#define PHASE_B(BI, QIV) do { \
    half8v hf_[8]; \
    _Pragma("unroll") for (int kt = 0; kt < 8; ++kt) { \
      int row_ = kt * 4 + g; \
      hf_[kt] = *(const half8v*)&hb[row_ * 128 + (((c + row_) & 15) << 3)]; } \
    f32x4 a2a_[2], a2b_[2]; \
    _Pragma("unroll") for (int mt = 0; mt < 2; ++mt) { a2a_[mt] = (f32x4){0,0,0,0}; a2b_[mt] = (f32x4){0,0,0,0}; } \
    _Pragma("unroll") for (int kt = 0; kt < 4; ++kt) \
      _Pragma("unroll") for (int mt = 0; mt < 2; ++mt) { \
        a2a_[mt] = MFMA32(w2f[mt][kt], hf_[kt], a2a_[mt]); \
        a2b_[mt] = MFMA32(w2f[mt][kt + 4], hf_[kt + 4], a2b_[mt]); } \
    f32x4 mv_[2]; \
    _Pragma("unroll") for (int mt = 0; mt < 2; ++mt) { \
      mv_[mt] = zreg[mt] + a2a_[mt] + a2b_[mt]; \
      if (wv < 2) mv_[mt] += ur##BI[mt]; } \
    EPILOG(BI, QIV, mv_); \
  } while (0)

#define KL_FIN(PBI, TPREV) do { \
    if (tid < 16) { \
      float v_ = qpp[PBI][tid] + qpp[PBI][16 + tid] + qpp[PBI][32 + tid] + qpp[PBI][48 + tid]; \
      v_ += __shfl_xor(v_, 1); v_ += __shfl_xor(v_, 2); \
      v_ += __shfl_xor(v_, 4); v_ += __shfl_xor(v_, 8); \
      if (tid == 0) out_kl[(size_t)b * 256 + (size_t)(TPREV)] = 0.03125f * v_ + kv##PBI; \
    } \
  } while (0)

  // ---------------- t = 0 ----------------
  STAGE(0);
  STAGE(1);
  {
    f32x4 mv0[2];
#pragma unroll
    for (int mt = 0; mt < 2; ++mt) {
      mv0[mt] = *(const f32x4*)&m_init[wv * 32 + mt * 16 + g * 4];
      if (wv < 2) mv0[mt] += ur0[mt];
    }
    half4v mh0[2], ml0[2];
#pragma unroll
    for (int kt = 0; kt < 2; ++kt)
#pragma unroll
      for (int j = 0; j < 4; ++j) {
        float x = mv0[kt][j];
        _Float16 h = (_Float16)x;
        mh0[kt][j] = h;
        ml0[kt][j] = (_Float16)(x - (float)h);
      }
    half4v ka0_, ka1_;
    KAH(0, 0, ka0_); KAH(0, 1, ka1_);
    f32x4 hz = {0, 0, 0, 0};
    hz = MFMA16(ka0_, mh0[0], hz); hz = MFMA16(ka1_, mh0[1], hz);
    hz = MFMA16(ka0_, ml0[0], hz); hz = MFMA16(ka1_, ml0[1], hz);
    *(f32x4*)&h2p[wv][c * 20 + g * 4] = hz;
    __syncthreads();
    EPILOG(0, qiv0, mv0);
    __syncthreads();
  }

  // ---------------- t = 1..254 (pairs) ----------------
  for (int t = 1; t < 255; t += 2) {
    KL_FIN(0, t - 1);
    STAGE(0);
    PHASE_A(1);
    __syncthreads();
    PHASE_B(1, qiv);
    __syncthreads();
    KL_FIN(1, t);
    STAGE(1);
    PHASE_A(0);
    __syncthreads();
    PHASE_B(0, qiv);
    __syncthreads();
  }
  // ---------------- t = 255 ----------------
  KL_FIN(0, 254);
  PHASE_A(1);
  __syncthreads();
  PHASE_B(1, qiv);
  __syncthreads();
  KL_FIN(1, 255);
}

extern "C" void kernel_launch(void* const* d_in, const int* in_sizes, int n_in,
                              void* d_out, int out_size, void* d_ws, size_t ws_size,
                              hipStream_t stream) {
  (void)in_sizes; (void)n_in; (void)out_size;
  const float* u   = (const float*)d_in[0];
  const float* kk  = (const float*)d_in[1];
  const float* Kg  = (const float*)d_in[2];
  const float* epz = (const float*)d_in[3];
  const float* epw = (const float*)d_in[4];
  const float* W1  = (const float*)d_in[5];
  const float* W2  = (const float*)d_in[6];
  const float* mi  = (const float*)d_in[7];
  const float* Qd  = (const float*)d_in[8];
  const float* Q0d = (const float*)d_in[9];

  float* out_zf = (float*)d_out;                      // (S,B,T,L)
  float* out_mf = out_zf + (size_t)33554432;          // (B,T,L)
  float* out_zp = out_mf + (size_t)2097152;           // (S,B,T,L)
  float* out_kl = out_zp + (size_t)33554432;          // (B,T)

  char* ws = (char*)d_ws;
  size_t off = 0;
  auto take = [&](size_t n) { char* p = ws + off; off += n; return p; };
  float*    Ainv = (float*)take(16777216);
  float*    klc  = (float*)take(65536);
  float*    cgp  = (float*)take(8388608);
  _Float16* pfb  = (_Float16*)take(67108864);
  _Float16* w2h  = (_Float16*)take(65536);
  bool zw = ws_size >= off + 134217728;
  float* zpcb = zw ? (float*)take(134217728) : nullptr;
  bool pk = zw && (ws_size >= off + 67108864);
  _Float16* kab = pk ? (_Float16*)take(67108864) : nullptr;
  bool rfws = ws_size >= off + 134217728;
  _Float16* rfb = rfws ? (_Float16*)take(134217728) : (_Float16*)out_zp;
  int wzp = rfws ? 1 : 0;

  kw2_kernel<<<128, 256, 0, stream>>>(W2, w2h);
  kprep1_kernel<<<4096, 256, 0, stream>>>(Kg, kk, u, Qd, Q0d, Ainv, klc, pfb, cgp);
  kprepR_kernel<<<4096, 256, 0, stream>>>(Kg, w2h, rfb, kab);
  kc_kernel<<<16384, 256, 0, stream>>>(Kg, epz, epw, Qd, Q0d, Ainv, out_zf, out_zp,
                                       zpcb, zw ? 1 : 0, wzp);
  if (pk)       kscan_kernel<true,  true ><<<64, 256, 0, stream>>>(u, Kg, W1, W2, mi, Qd, Q0d, pfb, cgp, rfb, kab, zpcb, klc, out_zf, out_mf, out_kl);
  else if (zw)  kscan_kernel<false, true ><<<64, 256, 0, stream>>>(u, Kg, W1, W2, mi, Qd, Q0d, pfb, cgp, rfb, kab, zpcb, klc, out_zf, out_mf, out_kl);
  else          kscan_kernel<false, false><<<64, 256, 0, stream>>>(u, Kg, W1, W2, mi, Qd, Q0d, pfb, cgp, rfb, kab, zpcb, klc, out_zf, out_mf, out_kl);
  if (!rfws) kzp_kernel<<<2048, 256, 0, stream>>>(epz, Qd, Q0d, out_zp);
}